// Round 2
// 133.872 us; speedup vs baseline: 1.0096x; 1.0096x over previous
//
#include <hip/hip_runtime.h>
#include <hip/hip_bf16.h>
#include <hip/hip_fp16.h>

// All float tensors fp32 (proven R1/R2). Output fp32.
// Tables store E* = exp(-logit) in FP16; edge computes
// sigma(a)-sigma(b) = (u-t)/((1+t)(1+u)) with t=ESP*ECS, u=EIP*ECI in packed
// fp16 front-end. R4: per-channel divisions replaced by a 2-level fraction
// pair-tree (n1/d1 + n2/d2 = (n1*d2+n2*d1)/(d1*d2)) computed in F32 via
// v_fma_mix (fp16 operands read directly) -> v_rcp count 8->2 per lane*k.
// R3's all-fp16 tree overflowed (D1=dn*dn > 65504 at modest sigma) -> NaN;
// f32 levels cannot overflow (max ~1e7). Denominators pre-scaled by 0.25
// (w_pred pre-scaled by 0.25; N2,D2 both ~s^4 so scales cancel exactly):
// dn = 0.25*(1+t)(1+u) in [0.25, ~2.5e3], fp16-safe (overflow needs ~9.6
// sigma joint on two logit sums). Reduction via DPP butterfly — no LDS pipe.
constexpr int EDGES = 250000;
constexpr int EMB   = 64;
constexpr int CNUM  = 128;
constexpr int NSTU  = 10000;
constexpr int NITEM = 50000;
constexpr int NCONC = 2048;

// workspace (_Float16): ESP | EIP | ECS | ECI | WH(w_pred*0.25 fp16, 128)
constexpr size_t ESP_OFF = 0;
constexpr size_t EIP_OFF = ESP_OFF + (size_t)NSTU  * CNUM;
constexpr size_t ECS_OFF = EIP_OFF + (size_t)NITEM * CNUM;
constexpr size_t ECI_OFF = ECS_OFF + (size_t)NCONC * CNUM;
constexpr size_t WH_OFF  = ECI_OFF + (size_t)NCONC * CNUM;

constexpr float NEG_LOG2E = -1.44269504088896340736f;

// proj job space: one wave per 16-row strip (conc strips: one wave per table)
constexpr int STU_JOBS  = NSTU  / 16;            // 625
constexpr int ITEM_JOBS = NITEM / 16;            // 3125
constexpr int CONC_JOBS = (NCONC / 16) * 2;      // 256
constexpr int NJOBS     = STU_JOBS + ITEM_JOBS + CONC_JOBS;  // 4006
constexpr int PROJ_BLKS = (NJOBS + 3) / 4;

typedef _Float16 h8 __attribute__((ext_vector_type(8)));
typedef _Float16 h4 __attribute__((ext_vector_type(4)));
typedef _Float16 h2 __attribute__((ext_vector_type(2)));
typedef float    f32x4 __attribute__((ext_vector_type(4)));

__device__ __forceinline__ h2 cvt2(float a, float b) {
#if __has_builtin(__builtin_amdgcn_cvt_pkrtz)
    return __builtin_bit_cast(h2, __builtin_amdgcn_cvt_pkrtz(a, b));
#else
    h2 r; r[0] = (_Float16)a; r[1] = (_Float16)b; return r;
#endif
}

__device__ __forceinline__ h8 pack8(float4 lo, float4 hi) {
    const h2 a = cvt2(lo.x, lo.y);
    const h2 b = cvt2(lo.z, lo.w);
    const h2 c = cvt2(hi.x, hi.y);
    const h2 d = cvt2(hi.z, hi.w);
    const h4 ab = __builtin_shufflevector(a, b, 0, 1, 2, 3);
    const h4 cd = __builtin_shufflevector(c, d, 0, 1, 2, 3);
    return __builtin_shufflevector(ab, cd, 0, 1, 2, 3, 4, 5, 6, 7);
}

// x += dpp-permuted x (full-rate VALU, no LDS pipe)
template <int CTRL>
__device__ __forceinline__ float dppadd(float x) {
    return x + __int_as_float(__builtin_amdgcn_update_dpp(
        0, __float_as_int(x), CTRL, 0xf, 0xf, true));
}

// ---- projection via MFMA: O[r,c] = exp(-dot(F[r,:], W[c, wcol:wcol+64])) ---
__global__ __launch_bounds__(256) void proj_mfma(
        const float* __restrict__ stuF, const float* __restrict__ itemF,
        const float* __restrict__ concF,
        const float* __restrict__ W_stu, const float* __restrict__ W_item,
        const float* __restrict__ w_pred,
        _Float16* __restrict__ ESP, _Float16* __restrict__ EIP,
        _Float16* __restrict__ ECS, _Float16* __restrict__ ECI,
        _Float16* __restrict__ WH) {
    const int tid  = threadIdx.x;
    const int lane = tid & 63;
    const int job  = blockIdx.x * 4 + (tid >> 6);
    if (job >= NJOBS) return;

    if (job == 0) {  // one wave converts w_pred (128 f32) to fp16, * 0.25
        const float2 wv2 = ((const float2*)w_pred)[lane];
        h2 wh; wh[0] = (_Float16)(wv2.x * 0.25f);
        wh[1] = (_Float16)(wv2.y * 0.25f);
        *(h2*)(WH + 2 * lane) = wh;
    }

    const float* F; const float* W; _Float16* O; int strip, wcol;
    if (job < STU_JOBS) {
        F = stuF;  W = W_stu;  O = ESP; strip = job; wcol = 0;
    } else if (job < STU_JOBS + ITEM_JOBS) {
        F = itemF; W = W_item; O = EIP; strip = job - STU_JOBS; wcol = 0;
    } else {
        const int g = job - STU_JOBS - ITEM_JOBS;
        F = concF; W = (g & 1) ? W_item : W_stu; O = (g & 1) ? ECI : ECS;
        strip = g >> 1; wcol = EMB;
    }

    const int m = lane & 15;       // A row / B channel / D col
    const int q = lane >> 4;       // quad
    const int row = strip * 16 + m;

    const float4* fa = (const float4*)(F + (size_t)row * EMB + q * 8);
    const float4* fb = (const float4*)(F + (size_t)row * EMB + 32 + q * 8);
    const h8 A0 = pack8(fa[0], fa[1]);
    const h8 A1 = pack8(fb[0], fb[1]);

    const int orow = strip * 16 + q * 4;

#pragma unroll
    for (int ct = 0; ct < 8; ++ct) {
        const int ch = ct * 16 + m;
        const float* wr = W + (size_t)ch * (2 * EMB) + wcol;
        const float4* wb0 = (const float4*)(wr + q * 8);
        const float4* wb1 = (const float4*)(wr + 32 + q * 8);
        const h8 B0 = pack8(wb0[0], wb0[1]);
        const h8 B1 = pack8(wb1[0], wb1[1]);

        f32x4 acc = {0.f, 0.f, 0.f, 0.f};
        acc = __builtin_amdgcn_mfma_f32_16x16x32_f16(A0, B0, acc, 0, 0, 0);
        acc = __builtin_amdgcn_mfma_f32_16x16x32_f16(A1, B1, acc, 0, 0, 0);

#pragma unroll
        for (int r = 0; r < 4; ++r) {
            const float e = __builtin_amdgcn_exp2f(acc[r] * NEG_LOG2E);
            O[(size_t)(orow + r) * CNUM + ct * 16 + m] = (_Float16)e;
        }
    }
}

__device__ __forceinline__ float sigm(float x) {
    return __builtin_amdgcn_rcpf(1.f + __builtin_amdgcn_exp2f(x * NEG_LOG2E));
}

// ---- edge phase: 4 edges/wave, 16 lanes/edge, lane owns 8 channels --------
__global__ __launch_bounds__(256) void edge_kernel(
        const int*  __restrict__ stu_idx,
        const int*  __restrict__ item_idx,
        const int4* __restrict__ conc_idx,
        const _Float16* __restrict__ ESP,
        const _Float16* __restrict__ EIP,
        const _Float16* __restrict__ ECS,
        const _Float16* __restrict__ ECI,
        const _Float16* __restrict__ WH,
        const float* __restrict__ b_pred,
        float* __restrict__ out) {
    const int lane = threadIdx.x & 63;
    const int wvg  = (blockIdx.x * blockDim.x + threadIdx.x) >> 6;
    const int sub  = lane >> 4;      // edge within wave 0..3
    const int li   = lane & 15;      // lane within edge; owns ch li*8..li*8+7
    const int e    = wvg * 4 + sub;  // grid sized exactly

    const int s  = stu_idx[e];
    const int it = item_idx[e];
    const int4 c4 = conc_idx[e];

    const h8 es = *(const h8*)(ESP + (size_t)s  * CNUM + li * 8);
    const h8 ei = *(const h8*)(EIP + (size_t)it * CNUM + li * 8);
    const h8 w8 = *(const h8*)(WH + li * 8);   // w_pred * 0.25 (pre-scaled)
    const float b = b_pred[0];

    const _Float16 O1 = (_Float16)1.f, QT = (_Float16)0.25f;
    const h8 ONE = {O1, O1, O1, O1, O1, O1, O1, O1};
    const h8 QV  = {QT, QT, QT, QT, QT, QT, QT, QT};

    const int ck[4] = {c4.x, c4.y, c4.z, c4.w};
    float p[4];
#pragma unroll
    for (int k = 0; k < 4; ++k) {
        const h8 cs = *(const h8*)(ECS + (size_t)ck[k] * CNUM + li * 8);
        const h8 ci = *(const h8*)(ECI + (size_t)ck[k] * CNUM + li * 8);
        const h8 t  = es * cs;               // e^-(sp+cs)   (v_pk_mul)
        const h8 u  = ei * ci;               // e^-(ip+ci)
        const h8 dq = t * QV + QV;           // 0.25*(1+t)   (v_pk_fma)
        const h8 du = u + ONE;               // (1+u)
        const h8 dn = dq * du;               // 0.25*den in [0.25, ~2.5e3]
        const h8 nm = w8 * (u - t);          // (0.25w)(u-t); scales cancel
        // pair-tree in F32 (v_fma_mix reads fp16 ops directly): 8 -> 4 -> 2
        float N1[4], D1[4];
#pragma unroll
        for (int i = 0; i < 4; ++i) {
            N1[i] = (float)nm[i] * (float)dn[i + 4]
                  + (float)nm[i + 4] * (float)dn[i];
            D1[i] = (float)dn[i] * (float)dn[i + 4];
        }
        const float N2a = N1[0] * D1[2] + N1[2] * D1[0];
        const float N2b = N1[1] * D1[3] + N1[3] * D1[1];
        const float D2a = D1[0] * D1[2];
        const float D2b = D1[1] * D1[3];
        // only 2 rcps per (lane,k) instead of 8
        p[k] = N2a * __builtin_amdgcn_rcpf(D2a)
             + N2b * __builtin_amdgcn_rcpf(D2b);
    }

    // 16-lane sum via DPP butterfly; xor-basis {1,2,7,15} spans the group.
#pragma unroll
    for (int j = 0; j < 4; ++j) p[j] = dppadd<0xB1>(p[j]);   // quad_perm xor1
#pragma unroll
    for (int j = 0; j < 4; ++j) p[j] = dppadd<0x4E>(p[j]);   // quad_perm xor2
#pragma unroll
    for (int j = 0; j < 4; ++j) p[j] = dppadd<0x141>(p[j]);  // row_half_mirror
#pragma unroll
    for (int j = 0; j < 4; ++j) p[j] = dppadd<0x140>(p[j]);  // row_mirror

    const float r = 0.25f * (sigm(p[0] + b) + sigm(p[1] + b) +
                             sigm(p[2] + b) + sigm(p[3] + b));
    if (li == 0) out[e] = r;
}

extern "C" void kernel_launch(void* const* d_in, const int* in_sizes, int n_in,
                              void* d_out, int out_size, void* d_ws, size_t ws_size,
                              hipStream_t stream) {
    const int* stu_idx  = (const int*)d_in[0];
    const int* item_idx = (const int*)d_in[1];
    const int* conc_idx = (const int*)d_in[2];
    const float* stu_fusion     = (const float*)d_in[3];
    const float* item_fusion    = (const float*)d_in[4];
    const float* concept_fusion = (const float*)d_in[5];
    const float* W_stu          = (const float*)d_in[6];
    const float* W_item         = (const float*)d_in[7];
    const float* w_pred         = (const float*)d_in[8];
    const float* b_pred         = (const float*)d_in[9];
    float* out = (float*)d_out;

    _Float16* ESP = (_Float16*)d_ws + ESP_OFF;
    _Float16* EIP = (_Float16*)d_ws + EIP_OFF;
    _Float16* ECS = (_Float16*)d_ws + ECS_OFF;
    _Float16* ECI = (_Float16*)d_ws + ECI_OFF;
    _Float16* WH  = (_Float16*)d_ws + WH_OFF;

    proj_mfma<<<PROJ_BLKS, 256, 0, stream>>>(
        stu_fusion, item_fusion, concept_fusion, W_stu, W_item, w_pred,
        ESP, EIP, ECS, ECI, WH);

    edge_kernel<<<EDGES / 16, 256, 0, stream>>>(
        stu_idx, item_idx, (const int4*)conc_idx,
        ESP, EIP, ECS, ECI, WH, b_pred, out);
}